// Round 4
// baseline (161.796 us; speedup 1.0000x reference)
//
#include <hip/hip_runtime.h>

// VP_lattice reverse step, B = 2^20 rows. Round-4: full coalescing.
// R1-R3 post-mortem: dur pinned at ~44us across fp64<->fp32, ILP 1<->2,
// VMEM<->LDS table gathers => bottleneck is TA line-split serialization of
// the streaming loads (scalar 36B-stride plat = ~36 lines/wave/instr,
// 24B-stride float2 = 24). Fix: every global access is 16B/lane coalesced.
//  Phase A: stage plat via LDS (float4 coalesced), per-row eigen solve
//           (all-fp32 Hoger-Carlson, validated R3), write vec+sched to LDS.
//  Phase B: threads re-map to float4 chunks of the flat 6N arrays;
//           lt/pl0/z/out via dwordx4; vec via ds_read_b128.

#define NUM_STEPS 1000

__global__ __launch_bounds__(256) void vp_lattice_kernel(
    const float* __restrict__ lt,
    const float* __restrict__ pl0,
    const float* __restrict__ plat,
    const float* __restrict__ alpha_bars,
    const float* __restrict__ betas,
    const float* __restrict__ sigmas,
    const float* __restrict__ z_noise,
    const int*   __restrict__ t,
    float* __restrict__ out,
    int n)                       // rows; grid = n/256 blocks
{
    __shared__ float sTabCoef[NUM_STEPS + 1];
    __shared__ float sTabScale[NUM_STEPS + 1];
    __shared__ float sTabSig[NUM_STEPS + 1];
    // union region: plat staging (2304 f) THEN vec(1536) + coef/scale/sig(3x256)
    __shared__ __align__(16) float sReg[2304];

    const int tid = threadIdx.x;
    const int bid = blockIdx.x;

    // ---- build schedule table (coalesced reads of 4KB tables, L2-hot) ----
    {
        float beta_last = betas[NUM_STEPS - 1];          // betas[-2]
        for (int j = tid; j <= NUM_STEPS; j += 256) {
            float alpha = 1.0f - fminf(betas[j], beta_last);
            sTabCoef[j]  = 1.0f / sqrtf(alpha + 1e-8f);
            sTabScale[j] = (1.0f - alpha) / sqrtf(1.0f - alpha_bars[j] + 1e-8f);
            sTabSig[j]   = (j > 1) ? sigmas[j] : 0.0f;
        }
    }

    // ---- stage plat: 256 rows = 576 float4, fully coalesced ----
    {
        const float4* plat4 = reinterpret_cast<const float4*>(plat);
        const size_t pb = (size_t)bid * 576;
        const size_t pmax = (size_t)n * 9 / 4;
        float4* s4 = reinterpret_cast<float4*>(sReg);
#pragma unroll
        for (int j = 0; j < 3; ++j) {
            int k = tid + j * 256;
            if (k < 576 && pb + k < pmax) s4[k] = plat4[pb + k];
        }
    }

    // row index + t load (coalesced dword) before the barrier
    const int row = bid * 256 + tid;
    int ti = (row < n) ? t[row] : 0;

    __syncthreads();

    // ---- phase A: per-row 3x3 sqrtm (registers) ----
    const float* A = sReg + tid * 9;       // stride 9 (odd) -> <=2-way, free
    float a00 = A[0], a01 = A[1], a02 = A[2];
    float a10 = A[3], a11 = A[4], a12 = A[5];
    float a20 = A[6], a21 = A[7], a22 = A[8];

    // M = A^T A
    float m00 = a00*a00 + a10*a10 + a20*a20;
    float m01 = a00*a01 + a10*a11 + a20*a21;
    float m02 = a00*a02 + a10*a12 + a20*a22;
    float m11 = a01*a01 + a11*a11 + a21*a21;
    float m12 = a01*a02 + a11*a12 + a21*a22;
    float m22 = a02*a02 + a12*a12 + a22*a22;

    // eigenvalues, cancellation-free trig form (validated R3)
    float q  = (m00 + m11 + m22) * (1.0f/3.0f);
    float b00 = m00 - q, b11 = m11 - q, b22 = m22 - q;
    float p1 = m01*m01 + m02*m02 + m12*m12;
    float p2 = b00*b00 + b11*b11 + b22*b22 + 2.0f*p1;
    float p  = sqrtf(p2 * (1.0f/6.0f));
    float detB = b00*(b11*b22 - m12*m12)
               - m01*(m01*b22 - m12*m02)
               + m02*(m01*m12 - b11*m02);
    float pinv = 1.0f / fmaxf(p, 1e-20f);
    float r = 0.5f * detB * pinv * pinv * pinv;
    r = fminf(fmaxf(r, -1.0f), 1.0f);
    float phi = acosf(r) * (1.0f/3.0f);
    float mu1 = q + 2.0f*p*cosf(phi);
    float mu3 = q + 2.0f*p*cosf(phi + 2.0943951023931953f);
    float mu2 = 3.0f*q - mu1 - mu3;
    float l1 = sqrtf(fmaxf(mu1, 0.0f));
    float l2 = sqrtf(fmaxf(mu2, 0.0f));
    float l3 = sqrtf(fmaxf(mu3, 0.0f));

    // U = sqrtm(M), Hoger-Carlson inverse-free
    float IU   = l1 + l2 + l3;
    float IIU  = l1*(l2 + l3) + l2*l3;
    float IIIU = l1*l2*l3;
    float denom = (l1 + l2) * (l1 + l3) * (l2 + l3);
    float dinv  = 1.0f / fmaxf(denom, 1e-25f);
    float sd = (IU*IU - IIU) * dinv;
    float td = IU * IIIU * dinv;
    float nd = -dinv;

    float mm00 = m00*m00 + m01*m01 + m02*m02;
    float mm01 = m00*m01 + m01*m11 + m02*m12;
    float mm02 = m00*m02 + m01*m12 + m02*m22;
    float mm11 = m01*m01 + m11*m11 + m12*m12;
    float mm12 = m01*m02 + m11*m12 + m12*m22;
    float mm22 = m02*m02 + m12*m12 + m22*m22;

    float v0 = nd*mm00 + sd*m00 + td;
    float v1 = nd*mm01 + sd*m01;
    float v2 = nd*mm02 + sd*m02;
    float v3 = nd*mm11 + sd*m11 + td;
    float v4 = nd*mm12 + sd*m12;
    float v5 = nd*mm22 + sd*m22 + td;

    float coefR  = sTabCoef[ti];
    float scaleR = sTabScale[ti];
    float sigR   = sTabSig[ti];

    __syncthreads();   // all plat reads done; sReg may be overwritten

    // write vec + per-row schedule into the reused region
    float* sVec   = sReg;            // [1536]
    float* sCoef  = sReg + 1536;     // [256]
    float* sScale = sReg + 1792;     // [256]
    float* sSig   = sReg + 2048;     // [256]
    {
        float* v = sVec + tid * 6;
        v[0] = v0; v[1] = v1; v[2] = v2; v[3] = v3; v[4] = v4; v[5] = v5;
        sCoef[tid] = coefR; sScale[tid] = scaleR; sSig[tid] = sigR;
    }
    __syncthreads();

    // ---- phase B: float4-chunk mapping over the flat 6N arrays ----
    const float4* lt4 = reinterpret_cast<const float4*>(lt);
    const float4* pl4 = reinterpret_cast<const float4*>(pl0);
    const float4* zn4 = reinterpret_cast<const float4*>(z_noise);
    float4* out4      = reinterpret_cast<float4*>(out);
    const size_t cbase  = (size_t)bid * 384;          // block's first chunk
    const size_t cmax   = (size_t)n * 6 / 4;

#pragma unroll
    for (int pass = 0; pass < 2; ++pass) {
        int lc = tid + pass * 256;                    // local chunk 0..383
        if (lc >= 384) break;
        size_t qg = cbase + lc;
        if (lc < 384 && qg < cmax) {
            int lf = lc * 4;                          // local float idx
            float4 l4 = lt4[qg];
            float4 p4 = pl4[qg];
            float4 z4 = zn4[qg];
            float4 vf = *reinterpret_cast<const float4*>(sVec + lf); // aligned

            int r0 = lf / 6;
            int c0 = lf - r0 * 6;
            int r1 = (lf + 3) / 6;
            float cf0 = sCoef[r0], sc0 = sScale[r0], sg0 = sSig[r0];
            float cf1 = sCoef[r1], sc1 = sScale[r1], sg1 = sSig[r1];

            float lv[4] = {l4.x, l4.y, l4.z, l4.w};
            float pv[4] = {p4.x, p4.y, p4.z, p4.w};
            float zv[4] = {z4.x, z4.y, z4.z, z4.w};
            float vv[4] = {vf.x, vf.y, vf.z, vf.w};
            float ov[4];
#pragma unroll
            for (int e = 0; e < 4; ++e) {
                bool second = (c0 + e) >= 6;
                float cf = second ? cf1 : cf0;
                float sc = second ? sc1 : sc0;
                float sg = second ? sg1 : sg0;
                float pn = lv[e] - 0.5f * (vv[e] + pv[e]);
                ov[e] = cf * (lv[e] - sc * pn) + sg * zv[e];
            }
            out4[qg] = make_float4(ov[0], ov[1], ov[2], ov[3]);
        }
    }
}

extern "C" void kernel_launch(void* const* d_in, const int* in_sizes, int n_in,
                              void* d_out, int out_size, void* d_ws, size_t ws_size,
                              hipStream_t stream) {
    const float* lt         = (const float*)d_in[0];
    const float* pl0        = (const float*)d_in[1];
    const float* plat       = (const float*)d_in[2];
    const float* alpha_bars = (const float*)d_in[3];
    const float* betas      = (const float*)d_in[4];
    const float* sigmas     = (const float*)d_in[5];
    const float* z_noise    = (const float*)d_in[6];
    const int*   t          = (const int*)d_in[7];
    float* out = (float*)d_out;

    int n = in_sizes[0] / 6;            // B rows (2^20, multiple of 256)
    int grid = (n + 255) / 256;         // one block per 256 rows
    vp_lattice_kernel<<<grid, 256, 0, stream>>>(
        lt, pl0, plat, alpha_bars, betas, sigmas, z_noise, t, out, n);
}